// Round 6
// baseline (4481.729 us; speedup 1.0000x reference)
//
#include <hip/hip_runtime.h>

// SimpleRNN (B=64,T=256,I=128,H=1024,L=3,O=2) — persistent pipelined MFMA, v6.
//
// v5 post-mortem (4.07 ms = 16 us/iter): latency chain of ~7 coherence-point
// round trips per self-recurrence iteration; the 4-block k-split partial
// exchange (store+ARR+election+load) is ~3 of them. MfmaUtil 5% (not compute),
// FETCH 1.2 GB << read model (loads served at LLC), WRITE 2x h-volume.
//
// v6: (a) 512-thread 8-wave blocks, 32-col groups, FULL K per block; B-frags
// VGPR-resident (128 regs/lane). No k-split -> no partial exchange at all.
// (b) below-layer/x GEMM half runs BEFORE the self-spin (only needs
// READY[L-1][t], ready long in advance) -> off the critical chain. Chain is
// now: observe -> self-A loads (2 drains) -> MFMA -> LDS reduce -> tanh ->
// h-store drain -> fire-and-forget READY add -> observe  (~3.5 RTs).
// (c) back-pressure polls hoisted pre-spin (monotone counters, acyclic deps).
// 96 blocks (3 layers x 32 col-groups), 1 block/CU, all resident.

typedef __attribute__((ext_vector_type(8))) short short8;
typedef __attribute__((ext_vector_type(4))) float float4v;
typedef __attribute__((ext_vector_type(4))) unsigned short ushort4v;

#define DEVFN static __device__ __forceinline__

// Device-coherent (LLC point) ops; no cache-maintenance instructions.
#define GLD(dst, ptr) \
  asm volatile("global_load_dwordx4 %0, %1, off sc0 sc1" : "=v"(dst) : "v"(ptr))
#define GST8(ptr, val) \
  asm volatile("global_store_dwordx2 %0, %1, off sc0 sc1" :: "v"(ptr), "v"(val) : "memory")
#define GDRAIN() do { asm volatile("s_waitcnt vmcnt(0)" ::: "memory"); \
                      __builtin_amdgcn_sched_barrier(0); } while (0)

DEVFN unsigned short f2bf(float f) {           // fp32 -> bf16 bits, RNE
  unsigned int u = __float_as_uint(f);
  u += 0x7FFFu + ((u >> 16) & 1u);
  return (unsigned short)(u >> 16);
}
DEVFN float bf2f(unsigned short h) { return __uint_as_float(((unsigned int)h) << 16); }

DEVFN void spin_ge(int* p, int want) {         // relaxed poll (proven v4/v5)
  while (__hip_atomic_load(p, __ATOMIC_RELAXED, __HIP_MEMORY_SCOPE_AGENT) < want)
    __builtin_amdgcn_s_sleep(1);
}

namespace rnncfg {
constexpr int  TT = 256, HH = 1024;
constexpr long WELEMS = 1024L * 1152 + 2L * 1024 * 2048;   // concat [Wx|Wh], 3 layers
constexpr long XELEMS = 64L * 256 * 128;
constexpr long HELEMS = 3L * 8 * 64 * HH;                  // h ring: 3 layers x 8 slots

constexpr long OFF_WHI  = 0;
constexpr long OFF_WLO  = OFF_WHI + WELEMS * 2;
constexpr long OFF_XHI  = OFF_WLO + WELEMS * 2;
constexpr long OFF_XLO  = OFF_XHI + XELEMS * 2;
constexpr long OFF_HHI  = OFF_XLO + XELEMS * 2;
constexpr long OFF_HLO  = OFF_HHI + HELEMS * 2;
constexpr long OFF_BIAS = OFF_HLO + HELEMS * 2;
constexpr long OFF_CNT  = OFF_BIAS + 3L * HH * 4;
constexpr long N_CNT    = 768;                             // READY[3][256], count to 32
constexpr long WS_NEED  = OFF_CNT + N_CNT * 4;             // ~36.2 MB (proven envelope)

constexpr int SLAB = 64 * 36;                              // padded f32 slab per wave
constexpr int SMEM_BYTES = 8 * SLAB * 4;                   // 73,728 B dynamic LDS
}

__global__ __launch_bounds__(256) void rnn_prep_kernel(
    const float* __restrict__ x,
    const float* __restrict__ wx0, const float* __restrict__ bx0,
    const float* __restrict__ wh0, const float* __restrict__ bh0,
    const float* __restrict__ wx,  const float* __restrict__ bx,
    const float* __restrict__ wh,  const float* __restrict__ bh,
    char* __restrict__ ws)
{
  using namespace rnncfg;
  unsigned short* WHI = (unsigned short*)(ws + OFF_WHI);
  unsigned short* WLO = (unsigned short*)(ws + OFF_WLO);
  unsigned short* XHI = (unsigned short*)(ws + OFF_XHI);
  unsigned short* XLO = (unsigned short*)(ws + OFF_XLO);
  float* BIAS = (float*)(ws + OFF_BIAS);
  int*   CNT  = (int*)(ws + OFF_CNT);
  const long i0 = (long)blockIdx.x * blockDim.x + threadIdx.x;
  const long st = (long)gridDim.x * blockDim.x;

  for (long i = i0; i < N_CNT; i += st) CNT[i] = 0;   // ws is 0xAA-poisoned

  for (long i = i0; i < 3 * HH; i += st) {            // fused bias = bx + bh
    int l = (int)(i >> 10), n = (int)(i & 1023);
    BIAS[i] = (l == 0) ? (bx0[n] + bh0[n]) : (bx[(l - 1) * HH + n] + bh[(l - 1) * HH + n]);
  }
  for (long i = i0; i < XELEMS; i += st) {            // x -> bf16 hi/lo
    float v = x[i];
    unsigned short h = f2bf(v);
    XHI[i] = h; XLO[i] = f2bf(v - bf2f(h));
  }
  for (long i = i0; i < WELEMS; i += st) {            // concat [Wx|Wh] -> bf16 hi/lo
    long j = i; int n, k; float v;
    if (j < 1179648L) {                               // layer 0: [1024][1152]
      n = (int)(j / 1152); k = (int)(j % 1152);
      v = (k < 128) ? wx0[n * 128 + k] : wh0[(long)n * 1024 + (k - 128)];
    } else if (j < 3276800L) {                        // layer 1: [1024][2048]
      j -= 1179648L; n = (int)(j / 2048); k = (int)(j % 2048);
      v = (k < 1024) ? wx[(long)n * 1024 + k] : wh[(long)n * 1024 + (k - 1024)];
    } else {                                          // layer 2: [1024][2048]
      j -= 3276800L; n = (int)(j / 2048); k = (int)(j % 2048);
      v = (k < 1024) ? wx[1048576L + (long)n * 1024 + k]
                     : wh[1048576L + (long)n * 1024 + (k - 1024)];
    }
    unsigned short h = f2bf(v);
    WHI[i] = h; WLO[i] = f2bf(v - bf2f(h));
  }
}

#define MFMA(a, b, c) __builtin_amdgcn_mfma_f32_16x16x32_bf16((a), (b), (c), 0, 0, 0)

template<int L>
DEVFN void run_block(char* __restrict__ ws, int tid, int cg, float* __restrict__ pbuf)
{
  using namespace rnncfg;
  constexpr long LWOFF = (L == 0) ? 0L : ((L == 1) ? 1179648L : 3276800L);
  constexpr int  KL    = (L == 0) ? 1152 : 2048;

  const unsigned short* WHI = (const unsigned short*)(ws + OFF_WHI);
  const unsigned short* WLO = (const unsigned short*)(ws + OFF_WLO);
  const unsigned short* XHI = (const unsigned short*)(ws + OFF_XHI);
  const unsigned short* XLO = (const unsigned short*)(ws + OFF_XLO);
  unsigned short* HHI = (unsigned short*)(ws + OFF_HHI);
  unsigned short* HLO = (unsigned short*)(ws + OFF_HLO);
  const float* BIAS = (const float*)(ws + OFF_BIAS);
  int* READY = (int*)(ws + OFF_CNT);                 // [3][256], 32 producers each

  const int lane = tid & 63, wv = tid >> 6;          // 8 waves
  const int rowb = lane & 15;                        // A row / B col within 16-tile
  const int kof  = (lane >> 4) * 8;                  // frag k sub-offset
  const int n0   = cg * 32;

  // ---- B fragments -> VGPRs for all 256 steps (cached loads; W is read-only).
  // Each wave owns k-slice [wv*128, wv*128+128) of each 1024-wide region.
  short8 ebh[2][4], ebl[2][4];   // early region (L0: x, ks=0 only; L>0: below)
  short8 sbh[2][4], sbl[2][4];   // self region
#pragma unroll
  for (int nt = 0; nt < 2; ++nt) {
    const long wr = LWOFF + (long)(n0 + nt * 16 + rowb) * KL;
    if constexpr (L == 0) {
      if (wv < 4) {                                  // x region: 128 k, 1 kstep/wave
        ebh[nt][0] = *(const short8*)(WHI + wr + wv * 32 + kof);
        ebl[nt][0] = *(const short8*)(WLO + wr + wv * 32 + kof);
      }
#pragma unroll
      for (int ks = 0; ks < 4; ++ks) {
        const int kc = 128 + wv * 128 + ks * 32 + kof;
        sbh[nt][ks] = *(const short8*)(WHI + wr + kc);
        sbl[nt][ks] = *(const short8*)(WLO + wr + kc);
      }
    } else {
#pragma unroll
      for (int ks = 0; ks < 4; ++ks) {
        const int kb = wv * 128 + ks * 32 + kof;
        ebh[nt][ks] = *(const short8*)(WHI + wr + kb);
        ebl[nt][ks] = *(const short8*)(WLO + wr + kb);
        sbh[nt][ks] = *(const short8*)(WHI + wr + 1024 + kb);
        sbl[nt][ks] = *(const short8*)(WLO + wr + 1024 + kb);
      }
    }
  }

  for (int t = 0; t < TT; ++t) {
    float4v acc[4][2];
#pragma unroll
    for (int mt = 0; mt < 4; ++mt)
#pragma unroll
      for (int nt = 0; nt < 2; ++nt) acc[mt][nt] = (float4v){0.f, 0.f, 0.f, 0.f};

    // ======== EARLY phase (off the self-recurrence chain) ========
    if constexpr (L == 0) {
      if (wv < 4) {                                  // x contribution
        short8 xh[4], xl[4];
#pragma unroll
        for (int mt = 0; mt < 4; ++mt) {
          const long xo = ((long)(mt * 16 + rowb) * 256 + t) * 128 + wv * 32 + kof;
          GLD(xh[mt], XHI + xo);
          GLD(xl[mt], XLO + xo);
        }
        GDRAIN();
#pragma unroll
        for (int mt = 0; mt < 4; ++mt)
#pragma unroll
          for (int nt = 0; nt < 2; ++nt) {
            acc[mt][nt] = MFMA(xh[mt], ebh[nt][0], acc[mt][nt]);
            acc[mt][nt] = MFMA(xh[mt], ebl[nt][0], acc[mt][nt]);
            acc[mt][nt] = MFMA(xl[mt], ebh[nt][0], acc[mt][nt]);
          }
      }
    } else {
      if (tid == 0) spin_ge(&READY[(L - 1) * 256 + t], 32);
      __syncthreads();
      const unsigned short* AH = HHI + (long)((L - 1) * 8 + (t & 7)) * 65536;
      const unsigned short* AL = HLO + (long)((L - 1) * 8 + (t & 7)) * 65536;
#pragma unroll
      for (int half = 0; half < 2; ++half) {
        short8 ah[2][4], al[2][4];
#pragma unroll
        for (int m2 = 0; m2 < 2; ++m2) {
          const int ao = ((half * 2 + m2) * 16 + rowb) * 1024 + wv * 128 + kof;
#pragma unroll
          for (int ks = 0; ks < 4; ++ks) { GLD(ah[m2][ks], AH + ao + ks * 32);
                                           GLD(al[m2][ks], AL + ao + ks * 32); }
        }
        GDRAIN();
#pragma unroll
        for (int m2 = 0; m2 < 2; ++m2)
#pragma unroll
          for (int ks = 0; ks < 4; ++ks)
#pragma unroll
            for (int nt = 0; nt < 2; ++nt) {
              acc[half * 2 + m2][nt] = MFMA(ah[m2][ks], ebh[nt][ks], acc[half * 2 + m2][nt]);
              acc[half * 2 + m2][nt] = MFMA(ah[m2][ks], ebl[nt][ks], acc[half * 2 + m2][nt]);
              acc[half * 2 + m2][nt] = MFMA(al[m2][ks], sbh[nt][ks], acc[half * 2 + m2][nt]);
            }
      }
    }

    // ======== self spin (+ hoisted back-pressure) ========
    if (tid == 0) {
      if (t > 0) spin_ge(&READY[L * 256 + t - 1], 32);
      // back-pressure for h slot (t&7) (holds h[L][t-8]): layer L+1 readers are
      // at stage t-8; same-layer readers covered by READY[L][t-1] monotonicity.
      if (L < 2 && t >= 8) spin_ge(&READY[(L + 1) * 256 + t - 8], 32);
    }
    __syncthreads();

    // ======== SELF phase (the critical chain) ========
    if (t > 0) {
      const unsigned short* SH = HHI + (long)(L * 8 + ((t - 1) & 7)) * 65536;
      const unsigned short* SL = HLO + (long)(L * 8 + ((t - 1) & 7)) * 65536;
#pragma unroll
      for (int half = 0; half < 2; ++half) {
        short8 ah[2][4], al[2][4];
#pragma unroll
        for (int m2 = 0; m2 < 2; ++m2) {
          const int ao = ((half * 2 + m2) * 16 + rowb) * 1024 + wv * 128 + kof;
#pragma unroll
          for (int ks = 0; ks < 4; ++ks) { GLD(ah[m2][ks], SH + ao + ks * 32);
                                           GLD(al[m2][ks], SL + ao + ks * 32); }
        }
        GDRAIN();
#pragma unroll
        for (int m2 = 0; m2 < 2; ++m2)
#pragma unroll
          for (int ks = 0; ks < 4; ++ks)
#pragma unroll
            for (int nt = 0; nt < 2; ++nt) {
              acc[half * 2 + m2][nt] = MFMA(ah[m2][ks], sbh[nt][ks], acc[half * 2 + m2][nt]);
              acc[half * 2 + m2][nt] = MFMA(ah[m2][ks], sbl[nt][ks], acc[half * 2 + m2][nt]);
              acc[half * 2 + m2][nt] = MFMA(al[m2][ks], sbh[nt][ks], acc[half * 2 + m2][nt]);
            }
      }
    }

    // ======== 8-wave LDS reduce + tanh + h-store + flag ========
#pragma unroll
    for (int mt = 0; mt < 4; ++mt)
#pragma unroll
      for (int nt = 0; nt < 2; ++nt)
#pragma unroll
        for (int r = 0; r < 4; ++r)
          pbuf[wv * SLAB + (mt * 16 + (lane >> 4) * 4 + r) * 36 + nt * 16 + rowb]
              = acc[mt][nt][r];
    __syncthreads();

    {
      const int row = tid >> 3, c0 = (tid & 7) * 4;  // 64 rows x 8 col-quads
      float4v s = *(const float4v*)(pbuf + row * 36 + c0);
#pragma unroll
      for (int w = 1; w < 8; ++w)
        s += *(const float4v*)(pbuf + w * SLAB + row * 36 + c0);
      ushort4v vhi, vlo;
#pragma unroll
      for (int j = 0; j < 4; ++j) {
        const float v = tanhf(s[j] + BIAS[L * 1024 + n0 + c0 + j]);
        const unsigned short hh = f2bf(v);
        vhi[j] = hh; vlo[j] = f2bf(v - bf2f(hh));
      }
      const long o = (long)(L * 8 + (t & 7)) * 65536 + row * 1024 + n0 + c0;
      GST8(HHI + o, vhi);
      GST8(HLO + o, vlo);
    }
    GDRAIN();
    __syncthreads();                                 // all 512 threads' h at LLC

    if (tid == 0)                                    // fire-and-forget release
      __hip_atomic_fetch_add(&READY[L * 256 + t], 1, __ATOMIC_RELAXED,
                             __HIP_MEMORY_SCOPE_AGENT);
  }
}

__global__ __launch_bounds__(512, 2) void rnn_pipeline_kernel(
    char* __restrict__ ws, const float* __restrict__ fcw,
    const float* __restrict__ fcb, float* __restrict__ out)
{
  using namespace rnncfg;
  extern __shared__ float pbuf[];                    // 8 slabs of [64][36] f32
  const int tid = threadIdx.x, bid = blockIdx.x;
  const int layer = bid >> 5, cg = bid & 31;         // 96 blocks

  if (layer == 0)      run_block<0>(ws, tid, cg, pbuf);
  else if (layer == 1) run_block<1>(ws, tid, cg, pbuf);
  else                 run_block<2>(ws, tid, cg, pbuf);

  // ---- final FC (fp32) by block 0 once layer 2, t=255 is complete
  if (bid == 0) {
    int* READY = (int*)(ws + OFF_CNT);
    if (tid == 0) spin_ge(&READY[2 * 256 + 255], 32);
    __syncthreads();
    if (tid < 128) {
      const unsigned short* HHI = (const unsigned short*)(ws + OFF_HHI);
      const unsigned short* HLO = (const unsigned short*)(ws + OFF_HLO);
      const int bb = tid >> 1, o = tid & 1;
      const unsigned short* hH = HHI + (long)(2 * 8 + 7) * 65536 + (long)bb * 1024;
      const unsigned short* hL = HLO + (long)(2 * 8 + 7) * 65536 + (long)bb * 1024;
      const float* w = fcw + o * 1024;
      float sum = fcb[o];
      for (int n = 0; n < 1024; n += 32) {           // 8 coherent loads in flight
        short8 vh[4], vl[4];
#pragma unroll
        for (int qq = 0; qq < 4; ++qq) { GLD(vh[qq], hH + n + qq * 8);
                                         GLD(vl[qq], hL + n + qq * 8); }
        GDRAIN();
#pragma unroll
        for (int qq = 0; qq < 4; ++qq)
#pragma unroll
          for (int j = 0; j < 8; ++j)
            sum += (bf2f((unsigned short)vh[qq][j]) + bf2f((unsigned short)vl[qq][j]))
                   * w[n + qq * 8 + j];
      }
      out[bb * 2 + o] = sum;
    }
  }
}

extern "C" void kernel_launch(void* const* d_in, const int* in_sizes, int n_in,
                              void* d_out, int out_size, void* d_ws, size_t ws_size,
                              hipStream_t stream)
{
  using namespace rnncfg;
  const float* x   = (const float*)d_in[0];
  const float* wx0 = (const float*)d_in[1];
  const float* bx0 = (const float*)d_in[2];
  const float* wh0 = (const float*)d_in[3];
  const float* bh0 = (const float*)d_in[4];
  const float* wx  = (const float*)d_in[5];
  const float* bx  = (const float*)d_in[6];
  const float* wh  = (const float*)d_in[7];
  const float* bh  = (const float*)d_in[8];
  const float* fcw = (const float*)d_in[9];
  const float* fcb = (const float*)d_in[10];
  char* ws = (char*)d_ws;
  float* out = (float*)d_out;

  if (ws_size < (size_t)WS_NEED) return;

  hipFuncSetAttribute(reinterpret_cast<const void*>(rnn_pipeline_kernel),
                      hipFuncAttributeMaxDynamicSharedMemorySize, SMEM_BYTES);

  rnn_prep_kernel<<<dim3(1024), dim3(256), 0, stream>>>(
      x, wx0, bx0, wh0, bh0, wx, bx, wh, bh, ws);
  rnn_pipeline_kernel<<<dim3(96), dim3(512), SMEM_BYTES, stream>>>(
      ws, fcw, fcb, out);
}